// Round 2
// baseline (1359.372 us; speedup 1.0000x reference)
//
#include <hip/hip_runtime.h>
#include <stdint.h>

#define DI __device__ __forceinline__

typedef __attribute__((ext_vector_type(8))) short bf16x8;
typedef __attribute__((ext_vector_type(4))) float f32x4;
typedef __attribute__((ext_vector_type(4))) int   i32x4;
typedef __attribute__((ext_vector_type(4))) float fvec4;
typedef __attribute__((ext_vector_type(8))) unsigned short u16x8;

constexpr int S2   = 2048;
constexpr int NHD  = 4096;   // NH*HD (q width)
constexpr int KVD  = 1024;   // NKV*HD
constexpr int QKVW = 6144;   // q+k+v fused width
constexpr int QKW  = 5120;   // q+k width (cols that get a lo-plane)
constexpr float SCALE_LOG2E = 0.08838834764831845f * 1.4426950408889634f; // 1/sqrt(128)*log2(e)

DI unsigned short f32_bf16(float f) {
    union { float f; unsigned u; } v; v.f = f;
    unsigned r = v.u + 0x7FFFu + ((v.u >> 16) & 1u);
    return (unsigned short)(r >> 16);
}
DI float bf16_f32(unsigned short h) {
    union { unsigned u; float f; } v; v.u = ((unsigned)h) << 16; return v.f;
}

DI void load_lds16(const void* g, void* l) {
    __builtin_amdgcn_global_load_lds(
        (const __attribute__((address_space(1))) void*)(uintptr_t)g,
        (__attribute__((address_space(3))) void*)(uintptr_t)l, 16, 0, 0);
}

// ---------------- W4 prep: write (q - z) exactly as bf16; copy scales -------
// (q-z) is an integer in [-15,15] -> exact in bf16. Scale applied in f32 in GEMM.
__global__ __launch_bounds__(256) void k_prep(const int* __restrict__ qw,
                                              const float* __restrict__ sc,
                                              const int* __restrict__ zp,
                                              unsigned short* __restrict__ outW,
                                              float* __restrict__ outS) {
    long long t = (long long)blockIdx.x * 256 + threadIdx.x;
    long long base = t * 8;
    int n = (int)(base >> 12);
    int g = (int)((base >> 7) & 31);
    int z = zp[n * 32 + g];
    i32x4 a = *(const i32x4*)(qw + base);
    i32x4 b = *(const i32x4*)(qw + base + 4);
    u16x8 o;
#pragma unroll
    for (int j = 0; j < 4; ++j) {
        o[j]     = f32_bf16((float)(a[j] - z));
        o[4 + j] = f32_bf16((float)(b[j] - z));
    }
    *(u16x8*)(outW + base) = o;
    if ((base & 127) == 0) outS[n * 32 + g] = sc[n * 32 + g];
}

// ---------------- plain dequant (for Wo; bf16 rounding fine there) ----------
__global__ __launch_bounds__(256) void k_dequant(const int* __restrict__ qw,
                                                 const float* __restrict__ sc,
                                                 const int* __restrict__ zp,
                                                 unsigned short* __restrict__ out) {
    long long t = (long long)blockIdx.x * 256 + threadIdx.x;
    long long base = t * 8;
    int n = (int)(base >> 12);
    int g = (int)((base >> 7) & 31);
    float s = sc[n * 32 + g];
    int   z = zp[n * 32 + g];
    i32x4 a = *(const i32x4*)(qw + base);
    i32x4 b = *(const i32x4*)(qw + base + 4);
    u16x8 o;
#pragma unroll
    for (int j = 0; j < 4; ++j) {
        o[j]     = f32_bf16((float)(a[j] - z) * s);
        o[4 + j] = f32_bf16((float)(b[j] - z) * s);
    }
    *(u16x8*)(out + base) = o;
}

// ---------------- high-precision W4 GEMM -----------------------------------
// C[M][N] = A_f32[M][K] * ((q-z)*s)[N][K]^T.
// A split in-register into bf16 hi+lo (hi+lo MFMAs for QK cols, hi-only for V
// cols). Weights fed as exact-integer bf16; f32 group scale applied to a
// per-group f32 partial accumulator every 128 K (4 BK steps).
// Writes Chi (bf16, all cols) and Clo (bf16 residual, cols < QKW).
__global__ __launch_bounds__(256) void k_gemm_w4(const float* __restrict__ A,
                                                 const unsigned short* __restrict__ W,
                                                 const float* __restrict__ S,
                                                 unsigned short* __restrict__ Chi,
                                                 unsigned short* __restrict__ Clo) {
    constexpr int K = 4096;
    __shared__ __align__(16) float          Af[128 * 32];
    __shared__ __align__(16) unsigned short Bl[128 * 32];
    const int m0 = blockIdx.y * 128, n0 = blockIdx.x * 128;
    const bool qk = (n0 < QKW);
    const int tid = threadIdx.x;
    const int wave = tid >> 6, lane = tid & 63;
    const int wm = wave >> 1, wn = wave & 1;
    const int lq = lane & 15, lg = lane >> 4;
    const int arow = lane >> 3, acol = (lane & 7) * 4;  // A: f32 tile, 1KB/issue = 8 rows
    const int brow = lane >> 2, bcol = (lane & 3) * 8;  // B: bf16 tile, 1KB/issue = 16 rows
    f32x4 acc[4][4] = {};

    for (int g = 0; g < 32; ++g) {
        f32x4 part[4][4] = {};
        for (int kk = 0; kk < 4; ++kk) {
            const int k0 = g * 128 + kk * 32;
            __syncthreads();
#pragma unroll
            for (int i = 0; i < 4; ++i) {
                const int r0 = (wave * 4 + i) * 8;
                load_lds16(A + (long long)(m0 + r0 + arow) * K + k0 + acol, Af + r0 * 32);
            }
#pragma unroll
            for (int i = 0; i < 2; ++i) {
                const int r0 = (wave * 2 + i) * 16;
                load_lds16(W + (long long)(n0 + r0 + brow) * K + k0 + bcol, Bl + r0 * 32);
            }
            __syncthreads();
            bf16x8 ah[4], al[4], bfr[4];
#pragma unroll
            for (int mi = 0; mi < 4; ++mi) {
                const float* p = Af + (wm * 64 + mi * 16 + lq) * 32 + lg * 8;
                f32x4 v0 = *(const f32x4*)p;
                f32x4 v1 = *(const f32x4*)(p + 4);
#pragma unroll
                for (int j = 0; j < 4; ++j) {
                    unsigned short h0 = f32_bf16(v0[j]);
                    unsigned short h1 = f32_bf16(v1[j]);
                    ah[mi][j]     = (short)h0;
                    ah[mi][4 + j] = (short)h1;
                    al[mi][j]     = (short)f32_bf16(v0[j] - bf16_f32(h0));
                    al[mi][4 + j] = (short)f32_bf16(v1[j] - bf16_f32(h1));
                }
            }
#pragma unroll
            for (int ni = 0; ni < 4; ++ni)
                bfr[ni] = *(const bf16x8*)(Bl + (wn * 64 + ni * 16 + lq) * 32 + lg * 8);
#pragma unroll
            for (int mi = 0; mi < 4; ++mi)
#pragma unroll
                for (int ni = 0; ni < 4; ++ni)
                    part[mi][ni] = __builtin_amdgcn_mfma_f32_16x16x32_bf16(ah[mi], bfr[ni], part[mi][ni], 0, 0, 0);
            if (qk) {
#pragma unroll
                for (int mi = 0; mi < 4; ++mi)
#pragma unroll
                    for (int ni = 0; ni < 4; ++ni)
                        part[mi][ni] = __builtin_amdgcn_mfma_f32_16x16x32_bf16(al[mi], bfr[ni], part[mi][ni], 0, 0, 0);
            }
        }
        float sg[4];
#pragma unroll
        for (int ni = 0; ni < 4; ++ni)
            sg[ni] = S[(n0 + wn * 64 + ni * 16 + lq) * 32 + g];
#pragma unroll
        for (int mi = 0; mi < 4; ++mi)
#pragma unroll
            for (int ni = 0; ni < 4; ++ni)
#pragma unroll
                for (int r = 0; r < 4; ++r)
                    acc[mi][ni][r] += part[mi][ni][r] * sg[ni];
    }
#pragma unroll
    for (int mi = 0; mi < 4; ++mi)
#pragma unroll
        for (int ni = 0; ni < 4; ++ni)
#pragma unroll
            for (int r = 0; r < 4; ++r) {
                const int row = m0 + wm * 64 + mi * 16 + lg * 4 + r;
                const int col = n0 + wn * 64 + ni * 16 + lq;
                const float v = acc[mi][ni][r];
                const unsigned short h = f32_bf16(v);
                Chi[(long long)row * QKVW + col] = h;
                if (qk) Clo[(long long)row * QKW + col] = f32_bf16(v - bf16_f32(h));
            }
}

// ---------------- bf16 GEMM (O-projection): C = A[M][K] * B[N][K]^T --------
template <typename CT>
__global__ __launch_bounds__(256) void k_gemm_bt(const unsigned short* __restrict__ A,
                                                 const unsigned short* __restrict__ B,
                                                 CT* __restrict__ C,
                                                 int N, int K) {
    __shared__ __align__(16) unsigned short Alds[128 * 32];
    __shared__ __align__(16) unsigned short Blds[128 * 32];
    const int m0 = blockIdx.y * 128, n0 = blockIdx.x * 128;
    const int tid  = threadIdx.x;
    const int wave = tid >> 6, lane = tid & 63;
    const int wm = wave >> 1, wn = wave & 1;
    const int lq = lane & 15, lg = lane >> 4;
    const int srow = lane >> 2, scol = (lane & 3) * 8;
    f32x4 acc[4][4] = {};

    for (int k0 = 0; k0 < K; k0 += 32) {
        __syncthreads();
#pragma unroll
        for (int it = 0; it < 2; ++it) {
            const int r0 = (wave * 2 + it) * 16;
            load_lds16(A + (long long)(m0 + r0 + srow) * K + k0 + scol, Alds + r0 * 32);
            load_lds16(B + (long long)(n0 + r0 + srow) * K + k0 + scol, Blds + r0 * 32);
        }
        __syncthreads();
        bf16x8 af[4], bfr[4];
#pragma unroll
        for (int i = 0; i < 4; ++i) {
            af[i]  = *(const bf16x8*)(Alds + (wm * 64 + i * 16 + lq) * 32 + lg * 8);
            bfr[i] = *(const bf16x8*)(Blds + (wn * 64 + i * 16 + lq) * 32 + lg * 8);
        }
#pragma unroll
        for (int mi = 0; mi < 4; ++mi)
#pragma unroll
            for (int ni = 0; ni < 4; ++ni)
                acc[mi][ni] = __builtin_amdgcn_mfma_f32_16x16x32_bf16(af[mi], bfr[ni], acc[mi][ni], 0, 0, 0);
    }
#pragma unroll
    for (int mi = 0; mi < 4; ++mi)
#pragma unroll
        for (int ni = 0; ni < 4; ++ni)
#pragma unroll
            for (int r = 0; r < 4; ++r) {
                int row = m0 + wm * 64 + mi * 16 + lg * 4 + r;
                int col = n0 + wn * 64 + ni * 16 + lq;
                float v = acc[mi][ni][r];
                if constexpr (sizeof(CT) == 2) C[(long long)row * N + col] = (CT)f32_bf16(v);
                else                           C[(long long)row * N + col] = v;
            }
}

// ---------------- V transpose: VT[hk][d][s] = V[s][hk*128+d] ----------------
__global__ __launch_bounds__(256) void k_transpose_v(const unsigned short* __restrict__ QKV,
                                                     unsigned short* __restrict__ VT) {
    __shared__ unsigned short tile[32][33];
    const int s0 = blockIdx.x * 32, d0 = blockIdx.y * 32, hk = blockIdx.z;
    const int tx = threadIdx.x & 31, ty = threadIdx.x >> 5;
#pragma unroll
    for (int j = 0; j < 4; ++j)
        tile[ty + j * 8][tx] =
            QKV[(long long)(s0 + ty + j * 8) * QKVW + QKW + hk * 128 + d0 + tx];
    __syncthreads();
#pragma unroll
    for (int j = 0; j < 4; ++j)
        VT[((long long)hk * 128 + d0 + ty + j * 8) * S2 + s0 + tx] = tile[tx][ty + j * 8];
}

// ---------------- causal GQA flash attention (hi/lo q,k) --------------------
// grid (S/64, NH). 4 waves/block, wave = 16 q rows. KV step 32.
// QK^T = qh*kh + ql*kh + qh*kl (3 MFMAs) -> scores accurate to ~f32.
__global__ __launch_bounds__(256) void k_attn(const unsigned short* __restrict__ Qhi,
                                              const unsigned short* __restrict__ Qlo,
                                              const unsigned short* __restrict__ VT,
                                              unsigned short* __restrict__ O) {
    __shared__ __align__(16) unsigned short P_lds[4][16][40];
    const int q0  = blockIdx.x * 64;
    const int h   = blockIdx.y;
    const int hkv = h >> 2;
    const int tid = threadIdx.x;
    const int wave = tid >> 6, lane = tid & 63;
    const int lq = lane & 15, lg = lane >> 4;
    const int q0w = q0 + wave * 16;

    bf16x8 qf[4], qlf[4];
    const unsigned short* qrow  = Qhi + (long long)(q0w + lq) * QKVW + h * 128;
    const unsigned short* qrowl = Qlo + (long long)(q0w + lq) * QKW  + h * 128;
#pragma unroll
    for (int kc = 0; kc < 4; ++kc) {
        qf[kc]  = *(const bf16x8*)(qrow  + kc * 32 + lg * 8);
        qlf[kc] = *(const bf16x8*)(qrowl + kc * 32 + lg * 8);
    }

    f32x4 oacc[8] = {};
    float m[4], l[4];
#pragma unroll
    for (int r = 0; r < 4; ++r) { m[r] = -1e30f; l[r] = 0.f; }

    const int jend = q0 + 64;
    for (int j0 = 0; j0 < jend; j0 += 32) {
        f32x4 s0v = {}, s1v = {};
        const unsigned short* krow0  = Qhi + (long long)(j0 + lq) * QKVW + NHD + hkv * 128;
        const unsigned short* krow1  = Qhi + (long long)(j0 + 16 + lq) * QKVW + NHD + hkv * 128;
        const unsigned short* krow0l = Qlo + (long long)(j0 + lq) * QKW  + NHD + hkv * 128;
        const unsigned short* krow1l = Qlo + (long long)(j0 + 16 + lq) * QKW  + NHD + hkv * 128;
#pragma unroll
        for (int kc = 0; kc < 4; ++kc) {
            bf16x8 kh0 = *(const bf16x8*)(krow0  + kc * 32 + lg * 8);
            bf16x8 kh1 = *(const bf16x8*)(krow1  + kc * 32 + lg * 8);
            bf16x8 kl0 = *(const bf16x8*)(krow0l + kc * 32 + lg * 8);
            bf16x8 kl1 = *(const bf16x8*)(krow1l + kc * 32 + lg * 8);
            s0v = __builtin_amdgcn_mfma_f32_16x16x32_bf16(qf[kc],  kh0, s0v, 0, 0, 0);
            s0v = __builtin_amdgcn_mfma_f32_16x16x32_bf16(qlf[kc], kh0, s0v, 0, 0, 0);
            s0v = __builtin_amdgcn_mfma_f32_16x16x32_bf16(qf[kc],  kl0, s0v, 0, 0, 0);
            s1v = __builtin_amdgcn_mfma_f32_16x16x32_bf16(qf[kc],  kh1, s1v, 0, 0, 0);
            s1v = __builtin_amdgcn_mfma_f32_16x16x32_bf16(qlf[kc], kh1, s1v, 0, 0, 0);
            s1v = __builtin_amdgcn_mfma_f32_16x16x32_bf16(qf[kc],  kl1, s1v, 0, 0, 0);
        }
        float alpha[4], p0a[4], p1a[4];
#pragma unroll
        for (int r = 0; r < 4; ++r) {
            const int qg = q0w + lg * 4 + r;
            float t0 = s0v[r] * SCALE_LOG2E;
            float t1 = s1v[r] * SCALE_LOG2E;
            if (j0 + lq > qg)      t0 = -INFINITY;
            if (j0 + 16 + lq > qg) t1 = -INFINITY;
            float mx = fmaxf(t0, t1);
            mx = fmaxf(mx, __shfl_xor(mx, 1));
            mx = fmaxf(mx, __shfl_xor(mx, 2));
            mx = fmaxf(mx, __shfl_xor(mx, 4));
            mx = fmaxf(mx, __shfl_xor(mx, 8));
            float mn = fmaxf(m[r], mx);
            alpha[r] = exp2f(m[r] - mn);
            float p0 = exp2f(t0 - mn);
            float p1 = exp2f(t1 - mn);
            float sm = p0 + p1;
            sm += __shfl_xor(sm, 1);
            sm += __shfl_xor(sm, 2);
            sm += __shfl_xor(sm, 4);
            sm += __shfl_xor(sm, 8);
            l[r] = l[r] * alpha[r] + sm;
            m[r] = mn;
            p0a[r] = p0; p1a[r] = p1;
        }
#pragma unroll
        for (int nb = 0; nb < 8; ++nb)
#pragma unroll
            for (int r = 0; r < 4; ++r) oacc[nb][r] *= alpha[r];
#pragma unroll
        for (int r = 0; r < 4; ++r) {
            P_lds[wave][lg * 4 + r][lq]      = f32_bf16(p0a[r]);
            P_lds[wave][lg * 4 + r][16 + lq] = f32_bf16(p1a[r]);
        }
        __syncthreads();
        bf16x8 pf = *(const bf16x8*)(&P_lds[wave][lq][lg * 8]);
#pragma unroll
        for (int nb = 0; nb < 8; ++nb) {
            const unsigned short* vtp =
                VT + ((long long)hkv * 128 + nb * 16 + lq) * S2 + j0 + lg * 8;
            bf16x8 vf = *(const bf16x8*)vtp;
            oacc[nb] = __builtin_amdgcn_mfma_f32_16x16x32_bf16(pf, vf, oacc[nb], 0, 0, 0);
        }
        __syncthreads();
    }
    float linv[4];
#pragma unroll
    for (int r = 0; r < 4; ++r) linv[r] = 1.0f / l[r];
#pragma unroll
    for (int nb = 0; nb < 8; ++nb)
#pragma unroll
        for (int r = 0; r < 4; ++r) {
            int row = q0w + lg * 4 + r;
            int col = h * 128 + nb * 16 + lq;
            O[(long long)row * NHD + col] = f32_bf16(oacc[nb][r] * linv[r]);
        }
}

extern "C" void kernel_launch(void* const* d_in, const int* in_sizes, int n_in,
                              void* d_out, int out_size, void* d_ws, size_t ws_size,
                              hipStream_t stream) {
    (void)in_sizes; (void)n_in; (void)out_size; (void)ws_size;
    const float* hs  = (const float*)d_in[0];
    const int*   qqw = (const int*)d_in[1];
    const float* qsc = (const float*)d_in[2];
    const int*   qzp = (const int*)d_in[3];
    const int*   kqw = (const int*)d_in[4];
    const float* ksc = (const float*)d_in[5];
    const int*   kzp = (const int*)d_in[6];
    const int*   vqw = (const int*)d_in[7];
    const float* vsc = (const float*)d_in[8];
    const int*   vzp = (const int*)d_in[9];
    const int*   oqw = (const int*)d_in[10];
    const float* osc = (const float*)d_in[11];
    const int*   ozp = (const int*)d_in[12];

    char* ws = (char*)d_ws;
    // ws layout (bytes):
    //   wbuf : 0          .. 50331648   (6144x4096 bf16: (q-z); later Wo dequant)
    //   qklo : 50331648   .. 71303168   (2048x5120 bf16 lo-plane of q,k)
    //   sbuf : 71303168   .. 72089600   (6144x32 f32 group scales)
    //   vt   : 72089600   .. 76283904   (8x128x2048 bf16 V^T)
    //   xatt : 76283904   .. 93061120   (2048x4096 bf16 attention output)
    unsigned short* wbuf = (unsigned short*)(ws);
    unsigned short* qklo = (unsigned short*)(ws + 50331648ULL);
    float*          sbuf = (float*)(ws + 71303168ULL);
    unsigned short* vt   = (unsigned short*)(ws + 72089600ULL);
    unsigned short* xatt = (unsigned short*)(ws + 76283904ULL);
    unsigned short* qkvhi = (unsigned short*)d_out;  // 2048x6144 bf16 scratch in d_out
    float* out = (float*)d_out;

    // weights: rows [0,4096)=Wq, [4096,5120)=Wk, [5120,6144)=Wv, exact (q-z) bf16 + f32 scales
    k_prep<<<8192, 256, 0, stream>>>(qqw, qsc, qzp, wbuf, sbuf);
    k_prep<<<2048, 256, 0, stream>>>(kqw, ksc, kzp, wbuf + (size_t)4096 * 4096, sbuf + 4096 * 32);
    k_prep<<<2048, 256, 0, stream>>>(vqw, vsc, vzp, wbuf + (size_t)5120 * 4096, sbuf + 5120 * 32);
    // fused QKV projection, high precision: hi plane (d_out) + lo plane for q,k (ws)
    k_gemm_w4<<<dim3(48, 16), 256, 0, stream>>>(hs, wbuf, sbuf, qkvhi, qklo);
    k_transpose_v<<<dim3(64, 4, 8), 256, 0, stream>>>(qkvhi, vt);
    // attention -> xatt
    k_attn<<<dim3(32, 32), 256, 0, stream>>>(qkvhi, qklo, vt, xatt);
    // O projection (plain bf16): d_out f32 = attn @ Wo^T
    k_dequant<<<8192, 256, 0, stream>>>(oqw, osc, ozp, wbuf);
    k_gemm_bt<float><<<dim3(32, 16), 256, 0, stream>>>(xatt, wbuf, out, 4096, 4096);
}

// Round 3
// 1319.428 us; speedup vs baseline: 1.0303x; 1.0303x over previous
//
#include <hip/hip_runtime.h>
#include <stdint.h>

#define DI __device__ __forceinline__

typedef __attribute__((ext_vector_type(8))) short bf16x8;
typedef __attribute__((ext_vector_type(4))) float f32x4;
typedef __attribute__((ext_vector_type(4))) int   i32x4;
typedef __attribute__((ext_vector_type(4))) float fvec4;
typedef __attribute__((ext_vector_type(8))) unsigned short u16x8;

constexpr int S2   = 2048;
constexpr int NHD  = 4096;   // NH*HD (q width)
constexpr int KVD  = 1024;   // NKV*HD
constexpr int QKVW = 6144;   // q+k+v fused width
constexpr int QKW  = 5120;   // q+k width (cols that get a lo-plane)
constexpr float SCALE_LOG2E = 0.08838834764831845f * 1.4426950408889634f; // 1/sqrt(128)*log2(e)

DI unsigned short f32_bf16(float f) {
    union { float f; unsigned u; } v; v.f = f;
    unsigned r = v.u + 0x7FFFu + ((v.u >> 16) & 1u);
    return (unsigned short)(r >> 16);
}
DI float bf16_f32(unsigned short h) {
    union { unsigned u; float f; } v; v.u = ((unsigned)h) << 16; return v.f;
}

DI void load_lds16(const void* g, void* l) {
    __builtin_amdgcn_global_load_lds(
        (const __attribute__((address_space(1))) void*)(uintptr_t)g,
        (__attribute__((address_space(3))) void*)(uintptr_t)l, 16, 0, 0);
}

// ---------------- W4 prep: write (q - z) exactly as bf16; copy scales -------
__global__ __launch_bounds__(256) void k_prep(const int* __restrict__ qw,
                                              const float* __restrict__ sc,
                                              const int* __restrict__ zp,
                                              unsigned short* __restrict__ outW,
                                              float* __restrict__ outS) {
    long long t = (long long)blockIdx.x * 256 + threadIdx.x;
    long long base = t * 8;
    int n = (int)(base >> 12);
    int g = (int)((base >> 7) & 31);
    int z = zp[n * 32 + g];
    i32x4 a = *(const i32x4*)(qw + base);
    i32x4 b = *(const i32x4*)(qw + base + 4);
    u16x8 o;
#pragma unroll
    for (int j = 0; j < 4; ++j) {
        o[j]     = f32_bf16((float)(a[j] - z));
        o[4 + j] = f32_bf16((float)(b[j] - z));
    }
    *(u16x8*)(outW + base) = o;
    if ((base & 127) == 0) outS[n * 32 + g] = sc[n * 32 + g];
}

// ---------------- plain dequant (for Wo) ------------------------------------
__global__ __launch_bounds__(256) void k_dequant(const int* __restrict__ qw,
                                                 const float* __restrict__ sc,
                                                 const int* __restrict__ zp,
                                                 unsigned short* __restrict__ out) {
    long long t = (long long)blockIdx.x * 256 + threadIdx.x;
    long long base = t * 8;
    int n = (int)(base >> 12);
    int g = (int)((base >> 7) & 31);
    float s = sc[n * 32 + g];
    int   z = zp[n * 32 + g];
    i32x4 a = *(const i32x4*)(qw + base);
    i32x4 b = *(const i32x4*)(qw + base + 4);
    u16x8 o;
#pragma unroll
    for (int j = 0; j < 4; ++j) {
        o[j]     = f32_bf16((float)(a[j] - z) * s);
        o[4 + j] = f32_bf16((float)(b[j] - z) * s);
    }
    *(u16x8*)(out + base) = o;
}

// ---------------- high-precision W4 GEMM -----------------------------------
__global__ __launch_bounds__(256) void k_gemm_w4(const float* __restrict__ A,
                                                 const unsigned short* __restrict__ W,
                                                 const float* __restrict__ S,
                                                 unsigned short* __restrict__ Chi,
                                                 unsigned short* __restrict__ Clo) {
    constexpr int K = 4096;
    __shared__ __align__(16) float          Af[128 * 32];
    __shared__ __align__(16) unsigned short Bl[128 * 32];
    const int m0 = blockIdx.y * 128, n0 = blockIdx.x * 128;
    const bool qk = (n0 < QKW);
    const int tid = threadIdx.x;
    const int wave = tid >> 6, lane = tid & 63;
    const int wm = wave >> 1, wn = wave & 1;
    const int lq = lane & 15, lg = lane >> 4;
    const int arow = lane >> 3, acol = (lane & 7) * 4;
    const int brow = lane >> 2, bcol = (lane & 3) * 8;
    f32x4 acc[4][4] = {};

    for (int g = 0; g < 32; ++g) {
        f32x4 part[4][4] = {};
        for (int kk = 0; kk < 4; ++kk) {
            const int k0 = g * 128 + kk * 32;
            __syncthreads();
#pragma unroll
            for (int i = 0; i < 4; ++i) {
                const int r0 = (wave * 4 + i) * 8;
                load_lds16(A + (long long)(m0 + r0 + arow) * K + k0 + acol, Af + r0 * 32);
            }
#pragma unroll
            for (int i = 0; i < 2; ++i) {
                const int r0 = (wave * 2 + i) * 16;
                load_lds16(W + (long long)(n0 + r0 + brow) * K + k0 + bcol, Bl + r0 * 32);
            }
            __syncthreads();
            bf16x8 ah[4], al[4], bfr[4];
#pragma unroll
            for (int mi = 0; mi < 4; ++mi) {
                const float* p = Af + (wm * 64 + mi * 16 + lq) * 32 + lg * 8;
                f32x4 v0 = *(const f32x4*)p;
                f32x4 v1 = *(const f32x4*)(p + 4);
#pragma unroll
                for (int j = 0; j < 4; ++j) {
                    unsigned short h0 = f32_bf16(v0[j]);
                    unsigned short h1 = f32_bf16(v1[j]);
                    ah[mi][j]     = (short)h0;
                    ah[mi][4 + j] = (short)h1;
                    al[mi][j]     = (short)f32_bf16(v0[j] - bf16_f32(h0));
                    al[mi][4 + j] = (short)f32_bf16(v1[j] - bf16_f32(h1));
                }
            }
#pragma unroll
            for (int ni = 0; ni < 4; ++ni)
                bfr[ni] = *(const bf16x8*)(Bl + (wn * 64 + ni * 16 + lq) * 32 + lg * 8);
#pragma unroll
            for (int mi = 0; mi < 4; ++mi)
#pragma unroll
                for (int ni = 0; ni < 4; ++ni)
                    part[mi][ni] = __builtin_amdgcn_mfma_f32_16x16x32_bf16(ah[mi], bfr[ni], part[mi][ni], 0, 0, 0);
            if (qk) {
#pragma unroll
                for (int mi = 0; mi < 4; ++mi)
#pragma unroll
                    for (int ni = 0; ni < 4; ++ni)
                        part[mi][ni] = __builtin_amdgcn_mfma_f32_16x16x32_bf16(al[mi], bfr[ni], part[mi][ni], 0, 0, 0);
            }
        }
        float sg[4];
#pragma unroll
        for (int ni = 0; ni < 4; ++ni)
            sg[ni] = S[(n0 + wn * 64 + ni * 16 + lq) * 32 + g];
#pragma unroll
        for (int mi = 0; mi < 4; ++mi)
#pragma unroll
            for (int ni = 0; ni < 4; ++ni)
#pragma unroll
                for (int r = 0; r < 4; ++r)
                    acc[mi][ni][r] += part[mi][ni][r] * sg[ni];
    }
#pragma unroll
    for (int mi = 0; mi < 4; ++mi)
#pragma unroll
        for (int ni = 0; ni < 4; ++ni)
#pragma unroll
            for (int r = 0; r < 4; ++r) {
                const int row = m0 + wm * 64 + mi * 16 + lg * 4 + r;
                const int col = n0 + wn * 64 + ni * 16 + lq;
                const float v = acc[mi][ni][r];
                const unsigned short h = f32_bf16(v);
                Chi[(long long)row * QKVW + col] = h;
                if (qk) Clo[(long long)row * QKW + col] = f32_bf16(v - bf16_f32(h));
            }
}

// ---------------- bf16 GEMM (O-projection) ----------------------------------
template <typename CT>
__global__ __launch_bounds__(256) void k_gemm_bt(const unsigned short* __restrict__ A,
                                                 const unsigned short* __restrict__ B,
                                                 CT* __restrict__ C,
                                                 int N, int K) {
    __shared__ __align__(16) unsigned short Alds[128 * 32];
    __shared__ __align__(16) unsigned short Blds[128 * 32];
    const int m0 = blockIdx.y * 128, n0 = blockIdx.x * 128;
    const int tid  = threadIdx.x;
    const int wave = tid >> 6, lane = tid & 63;
    const int wm = wave >> 1, wn = wave & 1;
    const int lq = lane & 15, lg = lane >> 4;
    const int srow = lane >> 2, scol = (lane & 3) * 8;
    f32x4 acc[4][4] = {};

    for (int k0 = 0; k0 < K; k0 += 32) {
        __syncthreads();
#pragma unroll
        for (int it = 0; it < 2; ++it) {
            const int r0 = (wave * 2 + it) * 16;
            load_lds16(A + (long long)(m0 + r0 + srow) * K + k0 + scol, Alds + r0 * 32);
            load_lds16(B + (long long)(n0 + r0 + srow) * K + k0 + scol, Blds + r0 * 32);
        }
        __syncthreads();
        bf16x8 af[4], bfr[4];
#pragma unroll
        for (int i = 0; i < 4; ++i) {
            af[i]  = *(const bf16x8*)(Alds + (wm * 64 + i * 16 + lq) * 32 + lg * 8);
            bfr[i] = *(const bf16x8*)(Blds + (wn * 64 + i * 16 + lq) * 32 + lg * 8);
        }
#pragma unroll
        for (int mi = 0; mi < 4; ++mi)
#pragma unroll
            for (int ni = 0; ni < 4; ++ni)
                acc[mi][ni] = __builtin_amdgcn_mfma_f32_16x16x32_bf16(af[mi], bfr[ni], acc[mi][ni], 0, 0, 0);
    }
#pragma unroll
    for (int mi = 0; mi < 4; ++mi)
#pragma unroll
        for (int ni = 0; ni < 4; ++ni)
#pragma unroll
            for (int r = 0; r < 4; ++r) {
                int row = m0 + wm * 64 + mi * 16 + lg * 4 + r;
                int col = n0 + wn * 64 + ni * 16 + lq;
                float v = acc[mi][ni][r];
                if constexpr (sizeof(CT) == 2) C[(long long)row * N + col] = (CT)f32_bf16(v);
                else                           C[(long long)row * N + col] = v;
            }
}

// ---------------- V transpose: VT[hk][d][s] = V[s][hk*128+d] ----------------
__global__ __launch_bounds__(256) void k_transpose_v(const unsigned short* __restrict__ QKV,
                                                     unsigned short* __restrict__ VT) {
    __shared__ unsigned short tile[32][33];
    const int s0 = blockIdx.x * 32, d0 = blockIdx.y * 32, hk = blockIdx.z;
    const int tx = threadIdx.x & 31, ty = threadIdx.x >> 5;
#pragma unroll
    for (int j = 0; j < 4; ++j)
        tile[ty + j * 8][tx] =
            QKV[(long long)(s0 + ty + j * 8) * QKVW + QKW + hk * 128 + d0 + tx];
    __syncthreads();
#pragma unroll
    for (int j = 0; j < 4; ++j)
        VT[((long long)hk * 128 + d0 + ty + j * 8) * S2 + s0 + tx] = tile[tx][ty + j * 8];
}

// ---------------- causal GQA flash attention (hi/lo q,k) --------------------
// grid (S/64, NH). 4 waves/block, wave = 16 q rows, fully independent waves:
// NO barriers (P_lds is wave-private; K/V read per-wave from global/L2).
// KVBLK=64 per iteration; per-wave causal trip count jend = q0w+16.
// Heaviest q-blocks dispatched first (reversed blockIdx.x).
__global__ __launch_bounds__(256) void k_attn(const unsigned short* __restrict__ Qhi,
                                              const unsigned short* __restrict__ Qlo,
                                              const unsigned short* __restrict__ VT,
                                              unsigned short* __restrict__ O) {
    __shared__ __align__(16) unsigned short P_lds[4][16][76];
    const int h   = blockIdx.y;
    const int hkv = h >> 2;
    const int tid = threadIdx.x;
    const int wave = tid >> 6, lane = tid & 63;
    const int lq = lane & 15, lg = lane >> 4;
    const int q0w = (int)(gridDim.x - 1 - blockIdx.x) * 64 + wave * 16;

    bf16x8 qf[4], qlf[4];
    const unsigned short* qrow  = Qhi + (long long)(q0w + lq) * QKVW + h * 128;
    const unsigned short* qrowl = Qlo + (long long)(q0w + lq) * QKW  + h * 128;
#pragma unroll
    for (int kc = 0; kc < 4; ++kc) {
        qf[kc]  = *(const bf16x8*)(qrow  + kc * 32 + lg * 8);
        qlf[kc] = *(const bf16x8*)(qrowl + kc * 32 + lg * 8);
    }

    f32x4 oacc[8] = {};
    float m[4], l[4];
#pragma unroll
    for (int r = 0; r < 4; ++r) { m[r] = -1e30f; l[r] = 0.f; }

    const int jend = q0w + 16;
    for (int j0 = 0; j0 < jend; j0 += 64) {
        f32x4 sv[4] = {};
#pragma unroll
        for (int jj = 0; jj < 4; ++jj) {
            const unsigned short* kro = Qhi + (long long)(j0 + jj * 16 + lq) * QKVW + NHD + hkv * 128;
            const unsigned short* krl = Qlo + (long long)(j0 + jj * 16 + lq) * QKW  + NHD + hkv * 128;
#pragma unroll
            for (int kc = 0; kc < 4; ++kc) {
                bf16x8 kh = *(const bf16x8*)(kro + kc * 32 + lg * 8);
                bf16x8 kl = *(const bf16x8*)(krl + kc * 32 + lg * 8);
                sv[jj] = __builtin_amdgcn_mfma_f32_16x16x32_bf16(qf[kc],  kh, sv[jj], 0, 0, 0);
                sv[jj] = __builtin_amdgcn_mfma_f32_16x16x32_bf16(qlf[kc], kh, sv[jj], 0, 0, 0);
                sv[jj] = __builtin_amdgcn_mfma_f32_16x16x32_bf16(qf[kc],  kl, sv[jj], 0, 0, 0);
            }
        }
        float alpha[4], pv[4][4];
#pragma unroll
        for (int r = 0; r < 4; ++r) {
            const int qg = q0w + lg * 4 + r;
            float t[4];
            float mx = -INFINITY;
#pragma unroll
            for (int jj = 0; jj < 4; ++jj) {
                t[jj] = sv[jj][r] * SCALE_LOG2E;
                if (j0 + jj * 16 + lq > qg) t[jj] = -INFINITY;
                mx = fmaxf(mx, t[jj]);
            }
            mx = fmaxf(mx, __shfl_xor(mx, 1));
            mx = fmaxf(mx, __shfl_xor(mx, 2));
            mx = fmaxf(mx, __shfl_xor(mx, 4));
            mx = fmaxf(mx, __shfl_xor(mx, 8));
            const float mn = fmaxf(m[r], mx);
            alpha[r] = exp2f(m[r] - mn);
            float sm = 0.f;
#pragma unroll
            for (int jj = 0; jj < 4; ++jj) { pv[r][jj] = exp2f(t[jj] - mn); sm += pv[r][jj]; }
            sm += __shfl_xor(sm, 1);
            sm += __shfl_xor(sm, 2);
            sm += __shfl_xor(sm, 4);
            sm += __shfl_xor(sm, 8);
            l[r] = l[r] * alpha[r] + sm;
            m[r] = mn;
        }
#pragma unroll
        for (int nb = 0; nb < 8; ++nb)
#pragma unroll
            for (int r = 0; r < 4; ++r) oacc[nb][r] *= alpha[r];
#pragma unroll
        for (int r = 0; r < 4; ++r)
#pragma unroll
            for (int jj = 0; jj < 4; ++jj)
                P_lds[wave][lg * 4 + r][jj * 16 + lq] = f32_bf16(pv[r][jj]);
        const bf16x8 pf0 = *(const bf16x8*)(&P_lds[wave][lq][lg * 8]);
        const bf16x8 pf1 = *(const bf16x8*)(&P_lds[wave][lq][32 + lg * 8]);
#pragma unroll
        for (int nb = 0; nb < 8; ++nb) {
            const unsigned short* vtp = VT + ((long long)hkv * 128 + nb * 16 + lq) * S2 + j0;
            bf16x8 vf0 = *(const bf16x8*)(vtp + lg * 8);
            bf16x8 vf1 = *(const bf16x8*)(vtp + 32 + lg * 8);
            oacc[nb] = __builtin_amdgcn_mfma_f32_16x16x32_bf16(pf0, vf0, oacc[nb], 0, 0, 0);
            oacc[nb] = __builtin_amdgcn_mfma_f32_16x16x32_bf16(pf1, vf1, oacc[nb], 0, 0, 0);
        }
    }
    float linv[4];
#pragma unroll
    for (int r = 0; r < 4; ++r) linv[r] = 1.0f / l[r];
#pragma unroll
    for (int nb = 0; nb < 8; ++nb)
#pragma unroll
        for (int r = 0; r < 4; ++r) {
            int row = q0w + lg * 4 + r;
            int col = h * 128 + nb * 16 + lq;
            O[(long long)row * NHD + col] = f32_bf16(oacc[nb][r] * linv[r]);
        }
}

extern "C" void kernel_launch(void* const* d_in, const int* in_sizes, int n_in,
                              void* d_out, int out_size, void* d_ws, size_t ws_size,
                              hipStream_t stream) {
    (void)in_sizes; (void)n_in; (void)out_size; (void)ws_size;
    const float* hs  = (const float*)d_in[0];
    const int*   qqw = (const int*)d_in[1];
    const float* qsc = (const float*)d_in[2];
    const int*   qzp = (const int*)d_in[3];
    const int*   kqw = (const int*)d_in[4];
    const float* ksc = (const float*)d_in[5];
    const int*   kzp = (const int*)d_in[6];
    const int*   vqw = (const int*)d_in[7];
    const float* vsc = (const float*)d_in[8];
    const int*   vzp = (const int*)d_in[9];
    const int*   oqw = (const int*)d_in[10];
    const float* osc = (const float*)d_in[11];
    const int*   ozp = (const int*)d_in[12];

    char* ws = (char*)d_ws;
    unsigned short* wbuf = (unsigned short*)(ws);
    unsigned short* qklo = (unsigned short*)(ws + 50331648ULL);
    float*          sbuf = (float*)(ws + 71303168ULL);
    unsigned short* vt   = (unsigned short*)(ws + 72089600ULL);
    unsigned short* xatt = (unsigned short*)(ws + 76283904ULL);
    unsigned short* qkvhi = (unsigned short*)d_out;  // 2048x6144 bf16 scratch in d_out
    float* out = (float*)d_out;

    k_prep<<<8192, 256, 0, stream>>>(qqw, qsc, qzp, wbuf, sbuf);
    k_prep<<<2048, 256, 0, stream>>>(kqw, ksc, kzp, wbuf + (size_t)4096 * 4096, sbuf + 4096 * 32);
    k_prep<<<2048, 256, 0, stream>>>(vqw, vsc, vzp, wbuf + (size_t)5120 * 4096, sbuf + 5120 * 32);
    k_gemm_w4<<<dim3(48, 16), 256, 0, stream>>>(hs, wbuf, sbuf, qkvhi, qklo);
    k_transpose_v<<<dim3(64, 4, 8), 256, 0, stream>>>(qkvhi, vt);
    k_attn<<<dim3(32, 32), 256, 0, stream>>>(qkvhi, qklo, vt, xatt);
    k_dequant<<<8192, 256, 0, stream>>>(oqw, osc, ozp, wbuf);
    k_gemm_bt<float><<<dim3(32, 16), 256, 0, stream>>>(xatt, wbuf, out, 4096, 4096);
}

// Round 4
// 500.740 us; speedup vs baseline: 2.7147x; 2.6350x over previous
//
#include <hip/hip_runtime.h>
#include <stdint.h>

#define DI __device__ __forceinline__

typedef __attribute__((ext_vector_type(8))) _Float16 f16x8;
typedef __attribute__((ext_vector_type(4))) float f32x4;
typedef __attribute__((ext_vector_type(4))) int   i32x4;
typedef __attribute__((ext_vector_type(4))) float fvec4;
typedef __attribute__((ext_vector_type(8))) unsigned short u16x8;
typedef __attribute__((ext_vector_type(4))) unsigned short u16x4;

constexpr int S2   = 2048;
constexpr int NHD  = 4096;   // NH*HD (q width)
constexpr int KVD  = 1024;   // NKV*HD
constexpr int QKVW = 6144;   // q+k+v fused width
constexpr float SCALE_LOG2E = 0.08838834764831845f * 1.4426950408889634f; // 1/sqrt(128)*log2(e)

DI unsigned short f32_f16(float f) {
    union { _Float16 h; unsigned short u; } v;
    v.h = (_Float16)f;
    return v.u;
}

DI f32x4 mfma16(f16x8 a, f16x8 b, f32x4 c) {
    return __builtin_amdgcn_mfma_f32_16x16x32_f16(a, b, c, 0, 0, 0);
}

DI void load_lds16(const void* g, void* l) {
    __builtin_amdgcn_global_load_lds(
        (const __attribute__((address_space(1))) void*)(uintptr_t)g,
        (__attribute__((address_space(3))) void*)(uintptr_t)l, 16, 0, 0);
}

// ---------------- cast f32 -> f16 ----------------
__global__ __launch_bounds__(256) void k_cast(const float* __restrict__ in,
                                              unsigned short* __restrict__ out) {
    int i = (blockIdx.x * 256 + threadIdx.x) * 4;
    fvec4 v = *(const fvec4*)(in + i);
    u16x4 o;
#pragma unroll
    for (int j = 0; j < 4; ++j) o[j] = f32_f16(v[j]);
    *(u16x4*)(out + i) = o;
}

// ---------------- W4 prep: (q - z) exact in f16; copy f32 scales ------------
__global__ __launch_bounds__(256) void k_prep(const int* __restrict__ qw,
                                              const float* __restrict__ sc,
                                              const int* __restrict__ zp,
                                              unsigned short* __restrict__ outW,
                                              float* __restrict__ outS) {
    long long t = (long long)blockIdx.x * 256 + threadIdx.x;
    long long base = t * 8;
    int n = (int)(base >> 12);
    int g = (int)((base >> 7) & 31);
    int z = zp[n * 32 + g];
    i32x4 a = *(const i32x4*)(qw + base);
    i32x4 b = *(const i32x4*)(qw + base + 4);
    u16x8 o;
#pragma unroll
    for (int j = 0; j < 4; ++j) {
        o[j]     = f32_f16((float)(a[j] - z));
        o[4 + j] = f32_f16((float)(b[j] - z));
    }
    *(u16x8*)(outW + base) = o;
    if ((base & 127) == 0) outS[n * 32 + g] = sc[n * 32 + g];
}

// ---------------- W4 GEMM (f16 in, f32 group-scaled acc) --------------------
// C[M][N] = A_f16[M][K] * ((q-z)*s)[N][K]^T. W fed as exact-integer f16;
// f32 group scale applied to per-group f32 partial acc every 128 K.
template <typename CT>
__global__ __launch_bounds__(256) void k_gemm_w4(const unsigned short* __restrict__ A,
                                                 const unsigned short* __restrict__ W,
                                                 const float* __restrict__ S,
                                                 CT* __restrict__ C, int N) {
    constexpr int K = 4096;
    __shared__ __align__(16) unsigned short Al[128 * 32];
    __shared__ __align__(16) unsigned short Bl[128 * 32];
    const int m0 = blockIdx.y * 128, n0 = blockIdx.x * 128;
    const int tid = threadIdx.x;
    const int wave = tid >> 6, lane = tid & 63;
    const int wm = wave >> 1, wn = wave & 1;
    const int lq = lane & 15, lg = lane >> 4;
    const int srow = lane >> 2, scol = (lane & 3) * 8;
    f32x4 acc[4][4] = {};

    for (int g = 0; g < 32; ++g) {
        f32x4 part[4][4] = {};
        for (int kk = 0; kk < 4; ++kk) {
            const int k0 = g * 128 + kk * 32;
            __syncthreads();
#pragma unroll
            for (int it = 0; it < 2; ++it) {
                const int r0 = (wave * 2 + it) * 16;
                load_lds16(A + (long long)(m0 + r0 + srow) * K + k0 + scol, Al + r0 * 32);
                load_lds16(W + (long long)(n0 + r0 + srow) * K + k0 + scol, Bl + r0 * 32);
            }
            __syncthreads();
            f16x8 af[4], bf[4];
#pragma unroll
            for (int i = 0; i < 4; ++i) {
                af[i] = *(const f16x8*)(Al + (wm * 64 + i * 16 + lq) * 32 + lg * 8);
                bf[i] = *(const f16x8*)(Bl + (wn * 64 + i * 16 + lq) * 32 + lg * 8);
            }
#pragma unroll
            for (int mi = 0; mi < 4; ++mi)
#pragma unroll
                for (int ni = 0; ni < 4; ++ni)
                    part[mi][ni] = mfma16(af[mi], bf[ni], part[mi][ni]);
        }
        float sg[4];
#pragma unroll
        for (int ni = 0; ni < 4; ++ni)
            sg[ni] = S[(n0 + wn * 64 + ni * 16 + lq) * 32 + g];
#pragma unroll
        for (int mi = 0; mi < 4; ++mi)
#pragma unroll
            for (int ni = 0; ni < 4; ++ni)
#pragma unroll
                for (int r = 0; r < 4; ++r)
                    acc[mi][ni][r] += part[mi][ni][r] * sg[ni];
    }
#pragma unroll
    for (int mi = 0; mi < 4; ++mi)
#pragma unroll
        for (int ni = 0; ni < 4; ++ni)
#pragma unroll
            for (int r = 0; r < 4; ++r) {
                const int row = m0 + wm * 64 + mi * 16 + lg * 4 + r;
                const int col = n0 + wn * 64 + ni * 16 + lq;
                const float v = acc[mi][ni][r];
                if constexpr (sizeof(CT) == 2) C[(long long)row * N + col] = (CT)f32_f16(v);
                else                           C[(long long)row * N + col] = v;
            }
}

// ---------------- V transpose: VT[hk][d][s] = V[s][hk*128+d] ----------------
__global__ __launch_bounds__(256) void k_transpose_v(const unsigned short* __restrict__ QKV,
                                                     unsigned short* __restrict__ VT) {
    __shared__ unsigned short tile[32][33];
    const int s0 = blockIdx.x * 32, d0 = blockIdx.y * 32, hk = blockIdx.z;
    const int tx = threadIdx.x & 31, ty = threadIdx.x >> 5;
#pragma unroll
    for (int j = 0; j < 4; ++j)
        tile[ty + j * 8][tx] =
            QKV[(long long)(s0 + ty + j * 8) * QKVW + (NHD + KVD) + hk * 128 + d0 + tx];
    __syncthreads();
#pragma unroll
    for (int j = 0; j < 4; ++j)
        VT[((long long)hk * 128 + d0 + ty + j * 8) * S2 + s0 + tx] = tile[tx][ty + j * 8];
}

// ---------------- causal GQA flash attention (cooperative, f16) -------------
// grid(512): bid -> (hkv = bid&7, tq = bid>>3); slice g = tq<32 ? tq : 63-(tq-32)
// so blocks b and b+256 get complementary causal work (uniform per-CU load).
// Block = 4 waves = the 4 GQA q-heads of hkv, all on the SAME 32 q-rows
// [32g, 32g+32). K(32x128) and V^T(128x32) tiles double-buffered in LDS via
// global_load_lds with XOR-swizzled source; ds_reads apply the same swizzle
// (conflict-free). Softmax f32 in-register, shfl_xor over 16 lanes.
__global__ __launch_bounds__(256, 2) void k_attn(const unsigned short* __restrict__ QKV,
                                                 const unsigned short* __restrict__ VT,
                                                 unsigned short* __restrict__ O) {
    __shared__ __align__(16) unsigned short Ks[2][32 * 128];
    __shared__ __align__(16) unsigned short Vs[2][128 * 32];
    __shared__ __align__(16) unsigned short Ps[4][32 * 40];
    const int bid = blockIdx.x;
    const int hkv = bid & 7;
    const int tq  = bid >> 3;
    const int g   = (tq < 32) ? tq : 63 - (tq - 32);
    const int nt  = g + 1;
    const int tid = threadIdx.x;
    const int w = tid >> 6, lane = tid & 63;
    const int lq = lane & 15, lg = lane >> 4;
    const int h = hkv * 4 + w;

    const unsigned short* Kg  = QKV + NHD + hkv * 128;
    const unsigned short* VTg = VT + (long long)hkv * 128 * S2;

    const int ksr = lane >> 4;          // K stage: row sub (0..3)
    const int ksc = lane & 15;          // K stage: 16B chunk (0..15)
    const int vsr = lane >> 2;          // V stage: row sub (0..15)
    const int vsc = lane & 3;           // V stage: 16B chunk (0..3)
    const int vsx = (lane >> 3) & 3;    // V stage: (row>>1)&3 swizzle bits

    // Q fragments (f16, hoisted; rows g*32 + rb*16 + lq)
    f16x8 qf[2][4];
#pragma unroll
    for (int rb = 0; rb < 2; ++rb) {
        const unsigned short* qp = QKV + (long long)(g * 32 + rb * 16 + lq) * QKVW + h * 128;
#pragma unroll
        for (int kc = 0; kc < 4; ++kc) qf[rb][kc] = *(const f16x8*)(qp + kc * 32 + lg * 8);
    }

    f32x4 oacc[2][8] = {};
    float m[2][4], l[2][4];
#pragma unroll
    for (int rb = 0; rb < 2; ++rb)
#pragma unroll
        for (int r = 0; r < 4; ++r) { m[rb][r] = -1e30f; l[rb][r] = 0.f; }

    // stage K (rows 8w..8w+7) and V^T (rows 32w..32w+31) for key-tile j0
    auto stage = [&](int j0, int b) {
#pragma unroll
        for (int i = 0; i < 2; ++i) {
            const int r = 8 * w + 4 * i + ksr;
            load_lds16(Kg + (long long)(j0 + r) * QKVW + ((ksc ^ (r & 7)) << 3),
                       &Ks[b][(8 * w + 4 * i) * 128]);
        }
#pragma unroll
        for (int i = 0; i < 2; ++i) {
            const int r = 32 * w + 16 * i + vsr;
            load_lds16(VTg + (long long)r * S2 + j0 + ((vsc ^ vsx) << 3),
                       &Vs[b][(32 * w + 16 * i) * 32]);
        }
    };

    stage(0, 0);
    int buf = 0;
    for (int t = 0; t < nt; ++t) {
        const int j0 = t * 32;
        __syncthreads();                       // staged tile t visible (vmcnt drained)
        if (t + 1 < nt) stage(j0 + 32, buf ^ 1);

        // QK^T: 32 q-rows x 32 keys
        f32x4 sv[2][2] = {};
#pragma unroll
        for (int kc = 0; kc < 4; ++kc)
#pragma unroll
            for (int jj = 0; jj < 2; ++jj) {
                const int c = (kc * 4 + lg) ^ (lq & 7);
                f16x8 kf = *(const f16x8*)&Ks[buf][(jj * 16 + lq) * 128 + c * 8];
                sv[0][jj] = mfma16(qf[0][kc], kf, sv[0][jj]);
                sv[1][jj] = mfma16(qf[1][kc], kf, sv[1][jj]);
            }

        // online softmax
        float alpha[2][4], p[2][4][2];
#pragma unroll
        for (int rb = 0; rb < 2; ++rb)
#pragma unroll
            for (int r = 0; r < 4; ++r) {
                const int qg = g * 32 + rb * 16 + lg * 4 + r;
                float t0 = sv[rb][0][r] * SCALE_LOG2E;
                float t1 = sv[rb][1][r] * SCALE_LOG2E;
                if (j0 + lq > qg)      t0 = -INFINITY;
                if (j0 + 16 + lq > qg) t1 = -INFINITY;
                float mx = fmaxf(t0, t1);
                mx = fmaxf(mx, __shfl_xor(mx, 1));
                mx = fmaxf(mx, __shfl_xor(mx, 2));
                mx = fmaxf(mx, __shfl_xor(mx, 4));
                mx = fmaxf(mx, __shfl_xor(mx, 8));
                const float mn = fmaxf(m[rb][r], mx);
                alpha[rb][r] = exp2f(m[rb][r] - mn);
                float p0 = exp2f(t0 - mn);
                float p1 = exp2f(t1 - mn);
                float sm = p0 + p1;
                sm += __shfl_xor(sm, 1);
                sm += __shfl_xor(sm, 2);
                sm += __shfl_xor(sm, 4);
                sm += __shfl_xor(sm, 8);
                l[rb][r] = l[rb][r] * alpha[rb][r] + sm;
                m[rb][r] = mn;
                p[rb][r][0] = p0; p[rb][r][1] = p1;
            }
#pragma unroll
        for (int rb = 0; rb < 2; ++rb)
#pragma unroll
            for (int nb = 0; nb < 8; ++nb)
#pragma unroll
                for (int r = 0; r < 4; ++r) oacc[rb][nb][r] *= alpha[rb][r];

        // P -> per-wave LDS (f16), then PV
#pragma unroll
        for (int rb = 0; rb < 2; ++rb)
#pragma unroll
            for (int r = 0; r < 4; ++r)
#pragma unroll
                for (int jj = 0; jj < 2; ++jj)
                    Ps[w][(rb * 16 + lg * 4 + r) * 40 + jj * 16 + lq] = f32_f16(p[rb][r][jj]);
        const f16x8 pf0 = *(const f16x8*)&Ps[w][lq * 40 + lg * 8];
        const f16x8 pf1 = *(const f16x8*)&Ps[w][(16 + lq) * 40 + lg * 8];
#pragma unroll
        for (int nb = 0; nb < 8; ++nb) {
            const int c = lg ^ ((lq >> 1) & 3);
            f16x8 vf = *(const f16x8*)&Vs[buf][(nb * 16 + lq) * 32 + c * 8];
            oacc[0][nb] = mfma16(pf0, vf, oacc[0][nb]);
            oacc[1][nb] = mfma16(pf1, vf, oacc[1][nb]);
        }
        __syncthreads();                       // all waves done reading buf
        buf ^= 1;
    }

    float linv[2][4];
#pragma unroll
    for (int rb = 0; rb < 2; ++rb)
#pragma unroll
        for (int r = 0; r < 4; ++r) linv[rb][r] = 1.0f / l[rb][r];
#pragma unroll
    for (int rb = 0; rb < 2; ++rb)
#pragma unroll
        for (int nb = 0; nb < 8; ++nb)
#pragma unroll
            for (int r = 0; r < 4; ++r) {
                const int row = g * 32 + rb * 16 + lg * 4 + r;
                const int col = h * 128 + nb * 16 + lq;
                O[(long long)row * NHD + col] = f32_f16(oacc[rb][nb][r] * linv[rb][r]);
            }
}

extern "C" void kernel_launch(void* const* d_in, const int* in_sizes, int n_in,
                              void* d_out, int out_size, void* d_ws, size_t ws_size,
                              hipStream_t stream) {
    (void)in_sizes; (void)n_in; (void)out_size; (void)ws_size;
    const float* hs  = (const float*)d_in[0];
    const int*   qqw = (const int*)d_in[1];
    const float* qsc = (const float*)d_in[2];
    const int*   qzp = (const int*)d_in[3];
    const int*   kqw = (const int*)d_in[4];
    const float* ksc = (const float*)d_in[5];
    const int*   kzp = (const int*)d_in[6];
    const int*   vqw = (const int*)d_in[7];
    const float* vsc = (const float*)d_in[8];
    const int*   vzp = (const int*)d_in[9];
    const int*   oqw = (const int*)d_in[10];
    const float* osc = (const float*)d_in[11];
    const int*   ozp = (const int*)d_in[12];

    char* ws = (char*)d_ws;
    // ws layout (bytes):
    //   x16  : 0        .. 16MB    (2048x4096 f16 activations)
    //   wbuf : 16MB     .. 64MB    (6144x4096 f16 (q-z); later Wo (q-z))
    //   sbuf : 64MB     .. 65MB    (6144x32 f32 group scales)
    //   vt   : 65MB     .. 69MB    (8x128x2048 f16 V^T)
    //   xatt : 69MB     .. 85MB    (2048x4096 f16 attention output)
    unsigned short* x16  = (unsigned short*)(ws);
    unsigned short* wbuf = (unsigned short*)(ws + (16ULL << 20));
    float*          sbuf = (float*)(ws + (64ULL << 20));
    unsigned short* vt   = (unsigned short*)(ws + (65ULL << 20));
    unsigned short* xatt = (unsigned short*)(ws + (69ULL << 20));
    unsigned short* qkv  = (unsigned short*)d_out;   // 2048x6144 f16 scratch in d_out
    float* out = (float*)d_out;

    k_cast<<<8192, 256, 0, stream>>>(hs, x16);
    // W4 prep: rows [0,4096)=Wq, [4096,5120)=Wk, [5120,6144)=Wv
    k_prep<<<8192, 256, 0, stream>>>(qqw, qsc, qzp, wbuf, sbuf);
    k_prep<<<2048, 256, 0, stream>>>(kqw, ksc, kzp, wbuf + (size_t)4096 * 4096, sbuf + 4096 * 32);
    k_prep<<<2048, 256, 0, stream>>>(vqw, vsc, vzp, wbuf + (size_t)5120 * 4096, sbuf + 5120 * 32);
    // fused QKV projection (f16, group-scaled)
    k_gemm_w4<unsigned short><<<dim3(48, 16), 256, 0, stream>>>(x16, wbuf, sbuf, qkv, QKVW);
    k_transpose_v<<<dim3(64, 4, 8), 256, 0, stream>>>(qkv, vt);
    // Wo prep (reuses wbuf/sbuf; QKV GEMM already done)
    k_prep<<<8192, 256, 0, stream>>>(oqw, osc, ozp, wbuf, sbuf);
    // attention -> xatt
    k_attn<<<512, 256, 0, stream>>>(qkv, vt, xatt);
    // O projection (W4 integer-exact, f32 out)
    k_gemm_w4<float><<<dim3(32, 16), 256, 0, stream>>>(xatt, wbuf, sbuf, out, 4096);
}

// Round 5
// 416.459 us; speedup vs baseline: 3.2641x; 1.2024x over previous
//
#include <hip/hip_runtime.h>
#include <stdint.h>

#define DI __device__ __forceinline__

typedef __attribute__((ext_vector_type(8))) _Float16 f16x8;
typedef __attribute__((ext_vector_type(4))) float f32x4;
typedef __attribute__((ext_vector_type(4))) int   i32x4;
typedef __attribute__((ext_vector_type(4))) float fvec4;
typedef __attribute__((ext_vector_type(8))) unsigned short u16x8;
typedef __attribute__((ext_vector_type(4))) unsigned short u16x4;

constexpr int S2   = 2048;
constexpr int NHD  = 4096;   // NH*HD (q width)
constexpr int KVD  = 1024;   // NKV*HD
constexpr int QKVW = 6144;   // q+k+v fused width
constexpr float SCALE_LOG2E = 0.08838834764831845f * 1.4426950408889634f; // 1/sqrt(128)*log2(e)

DI unsigned short f32_f16(float f) {
    union { _Float16 h; unsigned short u; } v;
    v.h = (_Float16)f;
    return v.u;
}

DI f32x4 mfma16(f16x8 a, f16x8 b, f32x4 c) {
    return __builtin_amdgcn_mfma_f32_16x16x32_f16(a, b, c, 0, 0, 0);
}

DI void load_lds16(const void* g, void* l) {
    __builtin_amdgcn_global_load_lds(
        (const __attribute__((address_space(1))) void*)(uintptr_t)g,
        (__attribute__((address_space(3))) void*)(uintptr_t)l, 16, 0, 0);
}

// ---------------- cast f32 -> f16 ----------------
__global__ __launch_bounds__(256) void k_cast(const float* __restrict__ in,
                                              unsigned short* __restrict__ out) {
    int i = (blockIdx.x * 256 + threadIdx.x) * 4;
    fvec4 v = *(const fvec4*)(in + i);
    u16x4 o;
#pragma unroll
    for (int j = 0; j < 4; ++j) o[j] = f32_f16(v[j]);
    *(u16x4*)(out + i) = o;
}

// ---------------- W4 dequant: (q - z) * s -> f16 ----------------------------
__global__ __launch_bounds__(256) void k_prep(const int* __restrict__ qw,
                                              const float* __restrict__ sc,
                                              const int* __restrict__ zp,
                                              unsigned short* __restrict__ outW) {
    long long t = (long long)blockIdx.x * 256 + threadIdx.x;
    long long base = t * 8;
    int n = (int)(base >> 12);
    int g = (int)((base >> 7) & 31);
    float s = sc[n * 32 + g];
    int   z = zp[n * 32 + g];
    i32x4 a = *(const i32x4*)(qw + base);
    i32x4 b = *(const i32x4*)(qw + base + 4);
    u16x8 o;
#pragma unroll
    for (int j = 0; j < 4; ++j) {
        o[j]     = f32_f16((float)(a[j] - z) * s);
        o[4 + j] = f32_f16((float)(b[j] - z) * s);
    }
    *(u16x8*)(outW + base) = o;
}

// ---------------- f16 GEMM: C[M][N] = A[M][K] * B[N][K]^T (m97 structure) ---
template <typename CT>
__global__ __launch_bounds__(256) void k_gemm(const unsigned short* __restrict__ A,
                                              const unsigned short* __restrict__ B,
                                              CT* __restrict__ C, int N) {
    constexpr int K = 4096;
    __shared__ __align__(16) unsigned short Al[128 * 32];
    __shared__ __align__(16) unsigned short Bl[128 * 32];
    const int m0 = blockIdx.y * 128, n0 = blockIdx.x * 128;
    const int tid = threadIdx.x;
    const int wave = tid >> 6, lane = tid & 63;
    const int wm = wave >> 1, wn = wave & 1;
    const int lq = lane & 15, lg = lane >> 4;
    const int srow = lane >> 2, scol = (lane & 3) * 8;
    f32x4 acc[4][4] = {};

    for (int k0 = 0; k0 < K; k0 += 32) {
        __syncthreads();
#pragma unroll
        for (int it = 0; it < 2; ++it) {
            const int r0 = (wave * 2 + it) * 16;
            load_lds16(A + (long long)(m0 + r0 + srow) * K + k0 + scol, Al + r0 * 32);
            load_lds16(B + (long long)(n0 + r0 + srow) * K + k0 + scol, Bl + r0 * 32);
        }
        __syncthreads();
        f16x8 af[4], bf[4];
#pragma unroll
        for (int i = 0; i < 4; ++i) {
            af[i] = *(const f16x8*)(Al + (wm * 64 + i * 16 + lq) * 32 + lg * 8);
            bf[i] = *(const f16x8*)(Bl + (wn * 64 + i * 16 + lq) * 32 + lg * 8);
        }
#pragma unroll
        for (int mi = 0; mi < 4; ++mi)
#pragma unroll
            for (int ni = 0; ni < 4; ++ni)
                acc[mi][ni] = mfma16(af[mi], bf[ni], acc[mi][ni]);
    }
#pragma unroll
    for (int mi = 0; mi < 4; ++mi)
#pragma unroll
        for (int ni = 0; ni < 4; ++ni)
#pragma unroll
            for (int r = 0; r < 4; ++r) {
                const int row = m0 + wm * 64 + mi * 16 + lg * 4 + r;
                const int col = n0 + wn * 64 + ni * 16 + lq;
                const float v = acc[mi][ni][r];
                if constexpr (sizeof(CT) == 2) C[(long long)row * N + col] = (CT)f32_f16(v);
                else                           C[(long long)row * N + col] = v;
            }
}

// ---------------- V transpose: VT[hk][d][s] = V[s][hk*128+d] ----------------
__global__ __launch_bounds__(256) void k_transpose_v(const unsigned short* __restrict__ QKV,
                                                     unsigned short* __restrict__ VT) {
    __shared__ unsigned short tile[32][33];
    const int s0 = blockIdx.x * 32, d0 = blockIdx.y * 32, hk = blockIdx.z;
    const int tx = threadIdx.x & 31, ty = threadIdx.x >> 5;
#pragma unroll
    for (int j = 0; j < 4; ++j)
        tile[ty + j * 8][tx] =
            QKV[(long long)(s0 + ty + j * 8) * QKVW + (NHD + KVD) + hk * 128 + d0 + tx];
    __syncthreads();
#pragma unroll
    for (int j = 0; j < 4; ++j)
        VT[((long long)hk * 128 + d0 + ty + j * 8) * S2 + s0 + tx] = tile[tx][ty + j * 8];
}

// ---------------- causal GQA flash attention (cooperative, f16) -------------
__global__ __launch_bounds__(256, 2) void k_attn(const unsigned short* __restrict__ QKV,
                                                 const unsigned short* __restrict__ VT,
                                                 unsigned short* __restrict__ O) {
    __shared__ __align__(16) unsigned short Ks[2][32 * 128];
    __shared__ __align__(16) unsigned short Vs[2][128 * 32];
    __shared__ __align__(16) unsigned short Ps[4][32 * 40];
    const int bid = blockIdx.x;
    const int hkv = bid & 7;
    const int tq  = bid >> 3;
    const int g   = (tq < 32) ? tq : 63 - (tq - 32);
    const int nt  = g + 1;
    const int tid = threadIdx.x;
    const int w = tid >> 6, lane = tid & 63;
    const int lq = lane & 15, lg = lane >> 4;
    const int h = hkv * 4 + w;

    const unsigned short* Kg  = QKV + NHD + hkv * 128;
    const unsigned short* VTg = VT + (long long)hkv * 128 * S2;

    const int ksr = lane >> 4;          // K stage: row sub (0..3)
    const int ksc = lane & 15;          // K stage: 16B chunk (0..15)
    const int vsr = lane >> 2;          // V stage: row sub (0..15)
    const int vsc = lane & 3;           // V stage: 16B chunk (0..3)
    const int vsx = (lane >> 3) & 3;    // V stage: (row>>1)&3 swizzle bits

    f16x8 qf[2][4];
#pragma unroll
    for (int rb = 0; rb < 2; ++rb) {
        const unsigned short* qp = QKV + (long long)(g * 32 + rb * 16 + lq) * QKVW + h * 128;
#pragma unroll
        for (int kc = 0; kc < 4; ++kc) qf[rb][kc] = *(const f16x8*)(qp + kc * 32 + lg * 8);
    }

    f32x4 oacc[2][8] = {};
    float m[2][4], l[2][4];
#pragma unroll
    for (int rb = 0; rb < 2; ++rb)
#pragma unroll
        for (int r = 0; r < 4; ++r) { m[rb][r] = -1e30f; l[rb][r] = 0.f; }

    auto stage = [&](int j0, int b) {
#pragma unroll
        for (int i = 0; i < 2; ++i) {
            const int r = 8 * w + 4 * i + ksr;
            load_lds16(Kg + (long long)(j0 + r) * QKVW + ((ksc ^ (r & 7)) << 3),
                       &Ks[b][(8 * w + 4 * i) * 128]);
        }
#pragma unroll
        for (int i = 0; i < 2; ++i) {
            const int r = 32 * w + 16 * i + vsr;
            load_lds16(VTg + (long long)r * S2 + j0 + ((vsc ^ vsx) << 3),
                       &Vs[b][(32 * w + 16 * i) * 32]);
        }
    };

    stage(0, 0);
    int buf = 0;
    for (int t = 0; t < nt; ++t) {
        const int j0 = t * 32;
        __syncthreads();
        if (t + 1 < nt) stage(j0 + 32, buf ^ 1);

        f32x4 sv[2][2] = {};
#pragma unroll
        for (int kc = 0; kc < 4; ++kc)
#pragma unroll
            for (int jj = 0; jj < 2; ++jj) {
                const int c = (kc * 4 + lg) ^ (lq & 7);
                f16x8 kf = *(const f16x8*)&Ks[buf][(jj * 16 + lq) * 128 + c * 8];
                sv[0][jj] = mfma16(qf[0][kc], kf, sv[0][jj]);
                sv[1][jj] = mfma16(qf[1][kc], kf, sv[1][jj]);
            }

        float alpha[2][4], p[2][4][2];
#pragma unroll
        for (int rb = 0; rb < 2; ++rb)
#pragma unroll
            for (int r = 0; r < 4; ++r) {
                const int qg = g * 32 + rb * 16 + lg * 4 + r;
                float t0 = sv[rb][0][r] * SCALE_LOG2E;
                float t1 = sv[rb][1][r] * SCALE_LOG2E;
                if (j0 + lq > qg)      t0 = -INFINITY;
                if (j0 + 16 + lq > qg) t1 = -INFINITY;
                float mx = fmaxf(t0, t1);
                mx = fmaxf(mx, __shfl_xor(mx, 1));
                mx = fmaxf(mx, __shfl_xor(mx, 2));
                mx = fmaxf(mx, __shfl_xor(mx, 4));
                mx = fmaxf(mx, __shfl_xor(mx, 8));
                const float mn = fmaxf(m[rb][r], mx);
                alpha[rb][r] = exp2f(m[rb][r] - mn);
                float p0 = exp2f(t0 - mn);
                float p1 = exp2f(t1 - mn);
                float sm = p0 + p1;
                sm += __shfl_xor(sm, 1);
                sm += __shfl_xor(sm, 2);
                sm += __shfl_xor(sm, 4);
                sm += __shfl_xor(sm, 8);
                l[rb][r] = l[rb][r] * alpha[rb][r] + sm;
                m[rb][r] = mn;
                p[rb][r][0] = p0; p[rb][r][1] = p1;
            }
#pragma unroll
        for (int rb = 0; rb < 2; ++rb)
#pragma unroll
            for (int nb = 0; nb < 8; ++nb)
#pragma unroll
                for (int r = 0; r < 4; ++r) oacc[rb][nb][r] *= alpha[rb][r];

#pragma unroll
        for (int rb = 0; rb < 2; ++rb)
#pragma unroll
            for (int r = 0; r < 4; ++r)
#pragma unroll
                for (int jj = 0; jj < 2; ++jj)
                    Ps[w][(rb * 16 + lg * 4 + r) * 40 + jj * 16 + lq] = f32_f16(p[rb][r][jj]);
        const f16x8 pf0 = *(const f16x8*)&Ps[w][lq * 40 + lg * 8];
        const f16x8 pf1 = *(const f16x8*)&Ps[w][(16 + lq) * 40 + lg * 8];
#pragma unroll
        for (int nb = 0; nb < 8; ++nb) {
            const int c = lg ^ ((lq >> 1) & 3);
            f16x8 vf = *(const f16x8*)&Vs[buf][(nb * 16 + lq) * 32 + c * 8];
            oacc[0][nb] = mfma16(pf0, vf, oacc[0][nb]);
            oacc[1][nb] = mfma16(pf1, vf, oacc[1][nb]);
        }
        __syncthreads();
        buf ^= 1;
    }

    float linv[2][4];
#pragma unroll
    for (int rb = 0; rb < 2; ++rb)
#pragma unroll
        for (int r = 0; r < 4; ++r) linv[rb][r] = 1.0f / l[rb][r];
#pragma unroll
    for (int rb = 0; rb < 2; ++rb)
#pragma unroll
        for (int nb = 0; nb < 8; ++nb)
#pragma unroll
            for (int r = 0; r < 4; ++r) {
                const int row = g * 32 + rb * 16 + lg * 4 + r;
                const int col = h * 128 + nb * 16 + lq;
                O[(long long)row * NHD + col] = f32_f16(oacc[rb][nb][r] * linv[rb][r]);
            }
}

extern "C" void kernel_launch(void* const* d_in, const int* in_sizes, int n_in,
                              void* d_out, int out_size, void* d_ws, size_t ws_size,
                              hipStream_t stream) {
    (void)in_sizes; (void)n_in; (void)out_size; (void)ws_size;
    const float* hs  = (const float*)d_in[0];
    const int*   qqw = (const int*)d_in[1];
    const float* qsc = (const float*)d_in[2];
    const int*   qzp = (const int*)d_in[3];
    const int*   kqw = (const int*)d_in[4];
    const float* ksc = (const float*)d_in[5];
    const int*   kzp = (const int*)d_in[6];
    const int*   vqw = (const int*)d_in[7];
    const float* vsc = (const float*)d_in[8];
    const int*   vzp = (const int*)d_in[9];
    const int*   oqw = (const int*)d_in[10];
    const float* osc = (const float*)d_in[11];
    const int*   ozp = (const int*)d_in[12];

    char* ws = (char*)d_ws;
    // ws layout (bytes):
    //   x16  : 0        .. 16MB    (2048x4096 f16 activations)
    //   wbuf : 16MB     .. 64MB    (6144x4096 f16 dequant W; later Wo)
    //   vt   : 65MB     .. 69MB    (8x128x2048 f16 V^T)
    //   xatt : 69MB     .. 85MB    (2048x4096 f16 attention output)
    unsigned short* x16  = (unsigned short*)(ws);
    unsigned short* wbuf = (unsigned short*)(ws + (16ULL << 20));
    unsigned short* vt   = (unsigned short*)(ws + (65ULL << 20));
    unsigned short* xatt = (unsigned short*)(ws + (69ULL << 20));
    unsigned short* qkv  = (unsigned short*)d_out;   // 2048x6144 f16 scratch in d_out
    float* out = (float*)d_out;

    k_cast<<<8192, 256, 0, stream>>>(hs, x16);
    // W4 dequant to f16: rows [0,4096)=Wq, [4096,5120)=Wk, [5120,6144)=Wv
    k_prep<<<8192, 256, 0, stream>>>(qqw, qsc, qzp, wbuf);
    k_prep<<<2048, 256, 0, stream>>>(kqw, ksc, kzp, wbuf + (size_t)4096 * 4096);
    k_prep<<<2048, 256, 0, stream>>>(vqw, vsc, vzp, wbuf + (size_t)5120 * 4096);
    // fused QKV projection (f16)
    k_gemm<unsigned short><<<dim3(48, 16), 256, 0, stream>>>(x16, wbuf, qkv, QKVW);
    k_transpose_v<<<dim3(64, 4, 8), 256, 0, stream>>>(qkv, vt);
    // Wo dequant (reuses wbuf; QKV GEMM already done)
    k_prep<<<8192, 256, 0, stream>>>(oqw, osc, ozp, wbuf);
    // attention -> xatt
    k_attn<<<512, 256, 0, stream>>>(qkv, vt, xatt);
    // O projection (f32 out)
    k_gemm<float><<<dim3(32, 16), 256, 0, stream>>>(xatt, wbuf, out, 4096);
}

// Round 6
// 382.879 us; speedup vs baseline: 3.5504x; 1.0877x over previous
//
#include <hip/hip_runtime.h>
#include <stdint.h>

#define DI __device__ __forceinline__

typedef __attribute__((ext_vector_type(8))) _Float16 f16x8;
typedef __attribute__((ext_vector_type(4))) float f32x4;
typedef __attribute__((ext_vector_type(4))) int   i32x4;
typedef __attribute__((ext_vector_type(4))) float fvec4;
typedef __attribute__((ext_vector_type(8))) unsigned short u16x8;
typedef __attribute__((ext_vector_type(4))) unsigned short u16x4;

constexpr int S2   = 2048;
constexpr int NHD  = 4096;   // NH*HD (q width)
constexpr int KVD  = 1024;   // NKV*HD
constexpr int QKVW = 6144;   // q+k+v fused width
constexpr float SCALE_LOG2E = 0.08838834764831845f * 1.4426950408889634f; // 1/sqrt(128)*log2(e)

DI unsigned short f32_f16(float f) {
    union { _Float16 h; unsigned short u; } v;
    v.h = (_Float16)f;
    return v.u;
}

DI f32x4 mfma16(f16x8 a, f16x8 b, f32x4 c) {
    return __builtin_amdgcn_mfma_f32_16x16x32_f16(a, b, c, 0, 0, 0);
}

DI void load_lds16(const void* g, void* l) {
    __builtin_amdgcn_global_load_lds(
        (const __attribute__((address_space(1))) void*)(uintptr_t)g,
        (__attribute__((address_space(3))) void*)(uintptr_t)l, 16, 0, 0);
}

// ---------------- cast f32 -> f16 ----------------
__global__ __launch_bounds__(256) void k_cast(const float* __restrict__ in,
                                              unsigned short* __restrict__ out) {
    int i = (blockIdx.x * 256 + threadIdx.x) * 4;
    fvec4 v = *(const fvec4*)(in + i);
    u16x4 o;
#pragma unroll
    for (int j = 0; j < 4; ++j) o[j] = f32_f16(v[j]);
    *(u16x4*)(out + i) = o;
}

// ---------------- W4 dequant: (q - z) * s -> f16 ----------------------------
__global__ __launch_bounds__(256) void k_prep(const int* __restrict__ qw,
                                              const float* __restrict__ sc,
                                              const int* __restrict__ zp,
                                              unsigned short* __restrict__ outW) {
    long long t = (long long)blockIdx.x * 256 + threadIdx.x;
    long long base = t * 8;
    int n = (int)(base >> 12);
    int g = (int)((base >> 7) & 31);
    float s = sc[n * 32 + g];
    int   z = zp[n * 32 + g];
    i32x4 a = *(const i32x4*)(qw + base);
    i32x4 b = *(const i32x4*)(qw + base + 4);
    u16x8 o;
#pragma unroll
    for (int j = 0; j < 4; ++j) {
        o[j]     = f32_f16((float)(a[j] - z) * s);
        o[4 + j] = f32_f16((float)(b[j] - z) * s);
    }
    *(u16x8*)(outW + base) = o;
}

// ---------------- f16 GEMM: C[M][N] = A[M][K] * B[N][K]^T (m97 structure) ---
template <typename CT>
__global__ __launch_bounds__(256) void k_gemm(const unsigned short* __restrict__ A,
                                              const unsigned short* __restrict__ B,
                                              CT* __restrict__ C, int N) {
    constexpr int K = 4096;
    __shared__ __align__(16) unsigned short Al[128 * 32];
    __shared__ __align__(16) unsigned short Bl[128 * 32];
    const int m0 = blockIdx.y * 128, n0 = blockIdx.x * 128;
    const int tid = threadIdx.x;
    const int wave = tid >> 6, lane = tid & 63;
    const int wm = wave >> 1, wn = wave & 1;
    const int lq = lane & 15, lg = lane >> 4;
    const int srow = lane >> 2, scol = (lane & 3) * 8;
    f32x4 acc[4][4] = {};

    for (int k0 = 0; k0 < K; k0 += 32) {
        __syncthreads();
#pragma unroll
        for (int it = 0; it < 2; ++it) {
            const int r0 = (wave * 2 + it) * 16;
            load_lds16(A + (long long)(m0 + r0 + srow) * K + k0 + scol, Al + r0 * 32);
            load_lds16(B + (long long)(n0 + r0 + srow) * K + k0 + scol, Bl + r0 * 32);
        }
        __syncthreads();
        f16x8 af[4], bf[4];
#pragma unroll
        for (int i = 0; i < 4; ++i) {
            af[i] = *(const f16x8*)(Al + (wm * 64 + i * 16 + lq) * 32 + lg * 8);
            bf[i] = *(const f16x8*)(Bl + (wn * 64 + i * 16 + lq) * 32 + lg * 8);
        }
#pragma unroll
        for (int mi = 0; mi < 4; ++mi)
#pragma unroll
            for (int ni = 0; ni < 4; ++ni)
                acc[mi][ni] = mfma16(af[mi], bf[ni], acc[mi][ni]);
    }
#pragma unroll
    for (int mi = 0; mi < 4; ++mi)
#pragma unroll
        for (int ni = 0; ni < 4; ++ni)
#pragma unroll
            for (int r = 0; r < 4; ++r) {
                const int row = m0 + wm * 64 + mi * 16 + lg * 4 + r;
                const int col = n0 + wn * 64 + ni * 16 + lq;
                const float v = acc[mi][ni][r];
                if constexpr (sizeof(CT) == 2) C[(long long)row * N + col] = (CT)f32_f16(v);
                else                           C[(long long)row * N + col] = v;
            }
}

// ---------------- V transpose: VT[hk][d][s] = V[s][hk*128+d] ----------------
__global__ __launch_bounds__(256) void k_transpose_v(const unsigned short* __restrict__ QKV,
                                                     unsigned short* __restrict__ VT) {
    __shared__ unsigned short tile[32][33];
    const int s0 = blockIdx.x * 32, d0 = blockIdx.y * 32, hk = blockIdx.z;
    const int tx = threadIdx.x & 31, ty = threadIdx.x >> 5;
#pragma unroll
    for (int j = 0; j < 4; ++j)
        tile[ty + j * 8][tx] =
            QKV[(long long)(s0 + ty + j * 8) * QKVW + (NHD + KVD) + hk * 128 + d0 + tx];
    __syncthreads();
#pragma unroll
    for (int j = 0; j < 4; ++j)
        VT[((long long)hk * 128 + d0 + ty + j * 8) * S2 + s0 + tx] = tile[tx][ty + j * 8];
}

// ---------------- causal GQA flash attention (cooperative, f16) -------------
// grid(1024): bid -> (hkv = bid&7, tq = bid>>3 in 0..127);
// g = tq<64 ? tq : 191-tq  (complementary causal pairing -> uniform CU load).
// Block = 4 waves = 4 GQA q-heads of hkv, each wave: 16 q-rows [16g,16g+16).
// K(32x128)/V^T(128x32) double-buffered in LDS (global_load_lds, XOR-swizzled
// source = swizzled ds_read, conflict-free). 37KB LDS + <=128 VGPR -> 4
// blocks/CU (16 waves/CU) for latency hiding. T13 defer-max (THR=8, log2).
__global__ __launch_bounds__(256, 4) void k_attn(const unsigned short* __restrict__ QKV,
                                                 const unsigned short* __restrict__ VT,
                                                 unsigned short* __restrict__ O) {
    __shared__ __align__(16) unsigned short Ks[2][32 * 128];
    __shared__ __align__(16) unsigned short Vs[2][128 * 32];
    __shared__ __align__(16) unsigned short Ps[4][16 * 40];
    const int bid = blockIdx.x;
    const int hkv = bid & 7;
    const int tq  = bid >> 3;
    const int g   = (tq < 64) ? tq : 191 - tq;
    const int nt  = (g >> 1) + 1;
    const int q0  = g * 16;
    const int tid = threadIdx.x;
    const int w = tid >> 6, lane = tid & 63;
    const int lq = lane & 15, lg = lane >> 4;
    const int h = hkv * 4 + w;

    const unsigned short* Kg  = QKV + NHD + hkv * 128;
    const unsigned short* VTg = VT + (long long)hkv * 128 * S2;

    const int ksr = lane >> 4;          // K stage: row sub (0..3)
    const int ksc = lane & 15;          // K stage: 16B chunk (0..15)
    const int vsr = lane >> 2;          // V stage: row sub (0..15)
    const int vsc = lane & 3;           // V stage: 16B chunk (0..3)
    const int vsx = (lane >> 3) & 3;    // V stage: (row>>1)&3 swizzle bits

    // Q fragments (f16, hoisted; rows q0 + lq)
    f16x8 qf[4];
    const unsigned short* qp = QKV + (long long)(q0 + lq) * QKVW + h * 128;
#pragma unroll
    for (int kc = 0; kc < 4; ++kc) qf[kc] = *(const f16x8*)(qp + kc * 32 + lg * 8);

    f32x4 oacc[8] = {};
    float m[4], l[4];
#pragma unroll
    for (int r = 0; r < 4; ++r) { m[r] = -1e30f; l[r] = 0.f; }

    auto stage = [&](int j0, int b) {
#pragma unroll
        for (int i = 0; i < 2; ++i) {
            const int r = 8 * w + 4 * i + ksr;
            load_lds16(Kg + (long long)(j0 + r) * QKVW + ((ksc ^ (r & 7)) << 3),
                       &Ks[b][(8 * w + 4 * i) * 128]);
        }
#pragma unroll
        for (int i = 0; i < 2; ++i) {
            const int r = 32 * w + 16 * i + vsr;
            load_lds16(VTg + (long long)r * S2 + j0 + ((vsc ^ vsx) << 3),
                       &Vs[b][(32 * w + 16 * i) * 32]);
        }
    };

    stage(0, 0);
    int buf = 0;
    for (int t = 0; t < nt; ++t) {
        const int j0 = t * 32;
        __syncthreads();                     // staged tile t visible
        if (t + 1 < nt) stage(j0 + 32, buf ^ 1);

        // QK^T: 16 q-rows x 32 keys
        f32x4 sv[2] = {};
#pragma unroll
        for (int kc = 0; kc < 4; ++kc)
#pragma unroll
            for (int jj = 0; jj < 2; ++jj) {
                const int c = (kc * 4 + lg) ^ (lq & 7);
                f16x8 kf = *(const f16x8*)&Ks[buf][(jj * 16 + lq) * 128 + c * 8];
                sv[jj] = mfma16(qf[kc], kf, sv[jj]);
            }

        // online softmax with defer-max (T13)
        float pmax[4], t0a[4], t1a[4];
#pragma unroll
        for (int r = 0; r < 4; ++r) {
            const int qg = q0 + lg * 4 + r;
            float t0 = sv[0][r] * SCALE_LOG2E;
            float t1 = sv[1][r] * SCALE_LOG2E;
            if (j0 + lq > qg)      t0 = -INFINITY;
            if (j0 + 16 + lq > qg) t1 = -INFINITY;
            float mx = fmaxf(t0, t1);
            mx = fmaxf(mx, __shfl_xor(mx, 1));
            mx = fmaxf(mx, __shfl_xor(mx, 2));
            mx = fmaxf(mx, __shfl_xor(mx, 4));
            mx = fmaxf(mx, __shfl_xor(mx, 8));
            pmax[r] = mx; t0a[r] = t0; t1a[r] = t1;
        }
        const bool grow = (pmax[0] > m[0] + 8.f) || (pmax[1] > m[1] + 8.f) ||
                          (pmax[2] > m[2] + 8.f) || (pmax[3] > m[3] + 8.f);
        if (__any(grow)) {
#pragma unroll
            for (int r = 0; r < 4; ++r) {
                const float mn = fmaxf(m[r], pmax[r]);
                const float alpha = exp2f(m[r] - mn);
                m[r] = mn;
                l[r] *= alpha;
#pragma unroll
                for (int nb = 0; nb < 8; ++nb) oacc[nb][r] *= alpha;
            }
        }
        float p0[4], p1[4];
#pragma unroll
        for (int r = 0; r < 4; ++r) {
            p0[r] = exp2f(t0a[r] - m[r]);
            p1[r] = exp2f(t1a[r] - m[r]);
            float sm = p0[r] + p1[r];
            sm += __shfl_xor(sm, 1);
            sm += __shfl_xor(sm, 2);
            sm += __shfl_xor(sm, 4);
            sm += __shfl_xor(sm, 8);
            l[r] += sm;
        }

        // P -> per-wave LDS (f16), then PV
#pragma unroll
        for (int r = 0; r < 4; ++r) {
            Ps[w][(lg * 4 + r) * 40 + lq]      = f32_f16(p0[r]);
            Ps[w][(lg * 4 + r) * 40 + 16 + lq] = f32_f16(p1[r]);
        }
        const f16x8 pf = *(const f16x8*)&Ps[w][lq * 40 + lg * 8];
#pragma unroll
        for (int nb = 0; nb < 8; ++nb) {
            const int c = lg ^ ((lq >> 1) & 3);
            f16x8 vf = *(const f16x8*)&Vs[buf][(nb * 16 + lq) * 32 + c * 8];
            oacc[nb] = mfma16(pf, vf, oacc[nb]);
        }
        __syncthreads();                     // all waves done reading buf
        buf ^= 1;
    }

    float linv[4];
#pragma unroll
    for (int r = 0; r < 4; ++r) linv[r] = 1.0f / l[r];
#pragma unroll
    for (int nb = 0; nb < 8; ++nb)
#pragma unroll
        for (int r = 0; r < 4; ++r) {
            const int row = q0 + lg * 4 + r;
            const int col = h * 128 + nb * 16 + lq;
            O[(long long)row * NHD + col] = f32_f16(oacc[nb][r] * linv[r]);
        }
}

extern "C" void kernel_launch(void* const* d_in, const int* in_sizes, int n_in,
                              void* d_out, int out_size, void* d_ws, size_t ws_size,
                              hipStream_t stream) {
    (void)in_sizes; (void)n_in; (void)out_size; (void)ws_size;
    const float* hs  = (const float*)d_in[0];
    const int*   qqw = (const int*)d_in[1];
    const float* qsc = (const float*)d_in[2];
    const int*   qzp = (const int*)d_in[3];
    const int*   kqw = (const int*)d_in[4];
    const float* ksc = (const float*)d_in[5];
    const int*   kzp = (const int*)d_in[6];
    const int*   vqw = (const int*)d_in[7];
    const float* vsc = (const float*)d_in[8];
    const int*   vzp = (const int*)d_in[9];
    const int*   oqw = (const int*)d_in[10];
    const float* osc = (const float*)d_in[11];
    const int*   ozp = (const int*)d_in[12];

    char* ws = (char*)d_ws;
    // ws layout (bytes):
    //   x16  : 0        .. 16MB    (2048x4096 f16 activations)
    //   wbuf : 16MB     .. 64MB    (6144x4096 f16 dequant W; later Wo)
    //   vt   : 65MB     .. 69MB    (8x128x2048 f16 V^T)
    //   xatt : 69MB     .. 85MB    (2048x4096 f16 attention output)
    unsigned short* x16  = (unsigned short*)(ws);
    unsigned short* wbuf = (unsigned short*)(ws + (16ULL << 20));
    unsigned short* vt   = (unsigned short*)(ws + (65ULL << 20));
    unsigned short* xatt = (unsigned short*)(ws + (69ULL << 20));
    unsigned short* qkv  = (unsigned short*)d_out;   // 2048x6144 f16 scratch in d_out
    float* out = (float*)d_out;

    k_cast<<<8192, 256, 0, stream>>>(hs, x16);
    // W4 dequant to f16: rows [0,4096)=Wq, [4096,5120)=Wk, [5120,6144)=Wv
    k_prep<<<8192, 256, 0, stream>>>(qqw, qsc, qzp, wbuf);
    k_prep<<<2048, 256, 0, stream>>>(kqw, ksc, kzp, wbuf + (size_t)4096 * 4096);
    k_prep<<<2048, 256, 0, stream>>>(vqw, vsc, vzp, wbuf + (size_t)5120 * 4096);
    // fused QKV projection (f16)
    k_gemm<unsigned short><<<dim3(48, 16), 256, 0, stream>>>(x16, wbuf, qkv, QKVW);
    k_transpose_v<<<dim3(64, 4, 8), 256, 0, stream>>>(qkv, vt);
    // Wo dequant (reuses wbuf; QKV GEMM already done)
    k_prep<<<8192, 256, 0, stream>>>(oqw, osc, ozp, wbuf);
    // attention -> xatt
    k_attn<<<1024, 256, 0, stream>>>(qkv, vt, xatt);
    // O projection (f32 out)
    k_gemm<float><<<dim3(32, 16), 256, 0, stream>>>(xatt, wbuf, out, 4096);
}